// Round 1
// baseline (180.716 us; speedup 1.0000x reference)
//
#include <hip/hip_runtime.h>
#include <hip/hip_bf16.h>

typedef short short8 __attribute__((ext_vector_type(8)));
typedef float f32x4 __attribute__((ext_vector_type(4)));
typedef __hip_bfloat16 bf16;

// Problem constants
// B=2, S=2048, D=1024, H=16, HD=64, 3D=3072, SCALE=1/8

// ---------------------------------------------------------------- cvt src
__global__ __launch_bounds__(256) void cvt_src_kernel(const float4* __restrict__ in,
                                                      bf16* __restrict__ out, int n4) {
  int i = blockIdx.x * 256 + threadIdx.x;
  if (i >= n4) return;
  float4 v = in[i];
  union { bf16 h[4]; uint2 u; } pk;
  pk.h[0] = __float2bfloat16(v.x);
  pk.h[1] = __float2bfloat16(v.y);
  pk.h[2] = __float2bfloat16(v.z);
  pk.h[3] = __float2bfloat16(v.w);
  *(uint2*)(out + (size_t)i * 4) = pk.u;
}

// ------------------------------------------------- transpose w -> bf16 B^T
// w: [1024][3072] fp32 -> wt: [3072][1024] bf16
__global__ __launch_bounds__(256) void transpose_w_kernel(const float* __restrict__ w,
                                                          bf16* __restrict__ wt) {
  __shared__ float tile[32][33];
  int x0 = blockIdx.x * 32;  // col of w (0..3071)
  int y0 = blockIdx.y * 32;  // row of w (0..1023)
  int tx = threadIdx.x & 31, ty = threadIdx.x >> 5;
#pragma unroll
  for (int i = 0; i < 4; i++) {
    int y = ty + i * 8;
    tile[y][tx] = w[(size_t)(y0 + y) * 3072 + x0 + tx];
  }
  __syncthreads();
#pragma unroll
  for (int i = 0; i < 4; i++) {
    int y = ty + i * 8;
    wt[(size_t)(x0 + y) * 1024 + y0 + tx] = __float2bfloat16(tile[tx][y]);
  }
}

// ------------------------------------------------------------ QKV GEMM
// A: src_bf [4096][1024], Bt: wt [3072][1024], C[m][n] = sum_k A[m][k]*Bt[n][k] + bias[n]
// Epilogue scatters into q_ws/k_ws [bh][s][64] and vt_ws [bh][64][s] (bf16).
__global__ __launch_bounds__(256) void qkv_gemm_kernel(
    const bf16* __restrict__ A, const bf16* __restrict__ Bt,
    const float* __restrict__ bias,
    bf16* __restrict__ q_ws, bf16* __restrict__ k_ws, bf16* __restrict__ vt_ws) {
  __shared__ alignas(16) bf16 As[128 * 72];  // [row][k] stride 72 (pad 8)
  __shared__ alignas(16) bf16 Bs[128 * 72];  // [outcol][k]
  const int tid = threadIdx.x;
  const int lane = tid & 63, wid = tid >> 6;
  const int lr = lane & 15, lg = lane >> 4;
  const int wm = wid >> 1, wn = wid & 1;  // 2x2 waves of 64x64
  const int m0 = blockIdx.x * 128, n0 = blockIdx.y * 128;

  const f32x4 z4 = {0.f, 0.f, 0.f, 0.f};
  f32x4 acc[4][4];
#pragma unroll
  for (int m = 0; m < 4; m++)
#pragma unroll
    for (int n = 0; n < 4; n++) acc[m][n] = z4;

  const int srow = tid >> 3;  // 0..31
  const int sseg = tid & 7;   // 0..7 (16B segments of a 128B row)

  for (int kt = 0; kt < 16; kt++) {
    const int k0 = kt * 64;
    __syncthreads();
#pragma unroll
    for (int i = 0; i < 4; i++) {
      int row = i * 32 + srow;
      *(short8*)&As[row * 72 + sseg * 8] =
          *(const short8*)&A[(size_t)(m0 + row) * 1024 + k0 + sseg * 8];
      *(short8*)&Bs[row * 72 + sseg * 8] =
          *(const short8*)&Bt[(size_t)(n0 + row) * 1024 + k0 + sseg * 8];
    }
    __syncthreads();
#pragma unroll
    for (int g = 0; g < 2; g++) {
      short8 af[4], bfr[4];
#pragma unroll
      for (int m = 0; m < 4; m++)
        af[m] = *(const short8*)&As[(wm * 64 + m * 16 + lr) * 72 + g * 32 + lg * 8];
#pragma unroll
      for (int n = 0; n < 4; n++)
        bfr[n] = *(const short8*)&Bs[(wn * 64 + n * 16 + lr) * 72 + g * 32 + lg * 8];
#pragma unroll
      for (int m = 0; m < 4; m++)
#pragma unroll
        for (int n = 0; n < 4; n++)
          acc[m][n] = __builtin_amdgcn_mfma_f32_16x16x32_bf16(af[m], bfr[n], acc[m][n], 0, 0, 0);
    }
  }

  // epilogue: C row = m0+wm*64+m*16+lg*4+r, col = n0+wn*64+n*16+lr
  const int which = n0 >> 10;  // 0=q 1=k 2=v (block-uniform: 1024 % 128 == 0)
#pragma unroll
  for (int m = 0; m < 4; m++) {
    int row = m0 + wm * 64 + m * 16 + lg * 4;
    int b = row >> 11;
    int ss0 = row & 2047;
#pragma unroll
    for (int n = 0; n < 4; n++) {
      int col = n0 + wn * 64 + n * 16 + lr;
      int d = col & 1023;
      int h = d >> 6, hd = d & 63;
      size_t bh = (size_t)(b * 16 + h);
      float bv = bias[col];
      if (which == 2) {
        union { bf16 h4[4]; uint2 u; } pk;
#pragma unroll
        for (int r = 0; r < 4; r++) pk.h4[r] = __float2bfloat16(acc[m][n][r] + bv);
        *(uint2*)&vt_ws[(bh * 64 + hd) * 2048 + ss0] = pk.u;  // 4 consecutive s
      } else {
        bf16* dst = (which == 0) ? q_ws : k_ws;
#pragma unroll
        for (int r = 0; r < 4; r++)
          dst[(bh * 2048 + (ss0 + r)) * 64 + hd] = __float2bfloat16(acc[m][n][r] + bv);
      }
    }
  }
}

// ------------------------------------------------------------ attention
// grid: (S/64, B*H). 4 waves/block, each wave owns 16 Q rows.
__global__ __launch_bounds__(256) void attn_kernel(
    const bf16* __restrict__ q_ws, const bf16* __restrict__ k_ws,
    const bf16* __restrict__ vt_ws, float* __restrict__ out) {
  __shared__ alignas(16) bf16 Ks[64 * 72];      // [key][dim] stride 72
  __shared__ alignas(16) bf16 Vs[64 * 72];      // [dim][key] stride 72 (V^T)
  __shared__ alignas(16) bf16 Ps[4][16 * 72];   // per-wave P tile [qrow][key]
  const int tid = threadIdx.x;
  const int lane = tid & 63, wid = tid >> 6;
  const int lr = lane & 15, lg = lane >> 4;
  const int bh = blockIdx.y;
  const int b = bh >> 4, h = bh & 15;
  const int q0 = blockIdx.x * 64;
  const float scale_l2e = 0.125f * 1.44269504088896f;  // SCALE * log2(e)

  // Q fragments (A operand): row = lr, k = g*32 + lg*8 + j
  short8 qf[2];
  {
    const bf16* qbase = q_ws + ((size_t)bh * 2048 + q0 + wid * 16 + lr) * 64;
    qf[0] = *(const short8*)(qbase + lg * 8);
    qf[1] = *(const short8*)(qbase + 32 + lg * 8);
  }

  const f32x4 z4 = {0.f, 0.f, 0.f, 0.f};
  f32x4 o[4];
#pragma unroll
  for (int n = 0; n < 4; n++) o[n] = z4;
  float mrow[4], lrow[4];
#pragma unroll
  for (int r = 0; r < 4; r++) { mrow[r] = -1e30f; lrow[r] = 0.f; }

  const int strow = tid >> 3, stseg = tid & 7;
  const bf16* kbase = k_ws + (size_t)bh * 2048 * 64;
  const bf16* vbase = vt_ws + (size_t)bh * 64 * 2048;

  for (int kt = 0; kt < 32; kt++) {
    __syncthreads();
#pragma unroll
    for (int i = 0; i < 2; i++) {
      int rr = i * 32 + strow;
      *(short8*)&Ks[rr * 72 + stseg * 8] =
          *(const short8*)&kbase[(size_t)(kt * 64 + rr) * 64 + stseg * 8];
      *(short8*)&Vs[rr * 72 + stseg * 8] =
          *(const short8*)&vbase[(size_t)rr * 2048 + kt * 64 + stseg * 8];
    }
    __syncthreads();

    // S = Q K^T : B operand B[k=dim][col=key] = Ks[key][dim]
    f32x4 sacc[4];
#pragma unroll
    for (int n = 0; n < 4; n++) sacc[n] = z4;
#pragma unroll
    for (int g = 0; g < 2; g++) {
      short8 kf[4];
#pragma unroll
      for (int n = 0; n < 4; n++)
        kf[n] = *(const short8*)&Ks[(n * 16 + lr) * 72 + g * 32 + lg * 8];
#pragma unroll
      for (int n = 0; n < 4; n++)
        sacc[n] = __builtin_amdgcn_mfma_f32_16x16x32_bf16(qf[g], kf[n], sacc[n], 0, 0, 0);
    }

    // online softmax (row r of this lane = q-row lg*4 + r; 16 lanes share a row)
    float mnew[4], resc[4], psum[4];
#pragma unroll
    for (int r = 0; r < 4; r++) {
      float mx = fmaxf(fmaxf(sacc[0][r], sacc[1][r]), fmaxf(sacc[2][r], sacc[3][r]));
#pragma unroll
      for (int off = 8; off; off >>= 1) mx = fmaxf(mx, __shfl_xor(mx, off));
      mx *= scale_l2e;
      mnew[r] = fmaxf(mrow[r], mx);
      resc[r] = exp2f(mrow[r] - mnew[r]);
      mrow[r] = mnew[r];
      psum[r] = 0.f;
    }
#pragma unroll
    for (int n = 0; n < 4; n++) {
#pragma unroll
      for (int r = 0; r < 4; r++) {
        float p = exp2f(sacc[n][r] * scale_l2e - mnew[r]);
        psum[r] += p;
        Ps[wid][(lg * 4 + r) * 72 + n * 16 + lr] = __float2bfloat16(p);
      }
    }
#pragma unroll
    for (int r = 0; r < 4; r++) {
      float sm = psum[r];
#pragma unroll
      for (int off = 8; off; off >>= 1) sm += __shfl_xor(sm, off);
      lrow[r] = lrow[r] * resc[r] + sm;
    }
#pragma unroll
    for (int n = 0; n < 4; n++) {
      f32x4 t = o[n];
#pragma unroll
      for (int r = 0; r < 4; r++) t[r] *= resc[r];
      o[n] = t;
    }

    // O += P V : A = P (row=lr, k=key), B[k=key][col=dim] = Vs[dim][key]
#pragma unroll
    for (int g = 0; g < 2; g++) {
      short8 pf = *(const short8*)&Ps[wid][lr * 72 + g * 32 + lg * 8];
      short8 vf[4];
#pragma unroll
      for (int n = 0; n < 4; n++)
        vf[n] = *(const short8*)&Vs[(n * 16 + lr) * 72 + g * 32 + lg * 8];
#pragma unroll
      for (int n = 0; n < 4; n++)
        o[n] = __builtin_amdgcn_mfma_f32_16x16x32_bf16(pf, vf[n], o[n], 0, 0, 0);
    }
  }

  // epilogue: out[b][s][h*64 + dim]
#pragma unroll
  for (int r = 0; r < 4; r++) {
    float inv = 1.f / lrow[r];
    int s = q0 + wid * 16 + lg * 4 + r;
#pragma unroll
    for (int n = 0; n < 4; n++) {
      int col = h * 64 + n * 16 + lr;
      out[((size_t)b * 2048 + s) * 1024 + col] = o[n][r] * inv;
    }
  }
}

// ---------------------------------------------------------------- launch
extern "C" void kernel_launch(void* const* d_in, const int* in_sizes, int n_in,
                              void* d_out, int out_size, void* d_ws, size_t ws_size,
                              hipStream_t stream) {
  (void)in_sizes; (void)n_in; (void)out_size; (void)ws_size;
  const float* src  = (const float*)d_in[0];   // [2,2048,1024]
  const float* w    = (const float*)d_in[1];   // [1024,3072]
  const float* bias = (const float*)d_in[2];   // [3072]
  float* out = (float*)d_out;

  char* ws = (char*)d_ws;
  bf16* src_bf = (bf16*)ws;                             // 4096*1024 = 8,388,608 B
  bf16* wt_bf  = (bf16*)(ws + 8388608);                 // 3072*1024 = 6,291,456 B
  bf16* q_ws   = (bf16*)(ws + 8388608 + 6291456);       // 32*2048*64
  bf16* k_ws   = q_ws + 4194304;
  bf16* vt_ws  = k_ws + 4194304;                        // total ~40 MB

  cvt_src_kernel<<<4096, 256, 0, stream>>>((const float4*)src, src_bf, 1048576);
  transpose_w_kernel<<<dim3(96, 32), 256, 0, stream>>>(w, wt_bf);
  qkv_gemm_kernel<<<dim3(32, 24), 256, 0, stream>>>(src_bf, wt_bf, bias, q_ws, k_ws, vt_ws);
  attn_kernel<<<dim3(32, 32), 256, 0, stream>>>(q_ws, k_ws, vt_ws, out);
}

// Round 3
// 117.517 us; speedup vs baseline: 1.5378x; 1.5378x over previous
//
#include <hip/hip_runtime.h>
#include <hip/hip_bf16.h>

typedef short short8 __attribute__((ext_vector_type(8)));
typedef float f32x4 __attribute__((ext_vector_type(4)));
typedef float f32x16 __attribute__((ext_vector_type(16)));
typedef __hip_bfloat16 bf16;

// Problem constants: B=2, S=2048, D=1024, H=16, HD=64, SCALE=1/8

__device__ __forceinline__ void glds16(const void* g, void* l) {
  __builtin_amdgcn_global_load_lds((const __attribute__((address_space(1))) unsigned int*)g,
                                   (__attribute__((address_space(3))) unsigned int*)l, 16, 0, 0);
}

// ---------------------------------------------------------------- cvt src
__global__ __launch_bounds__(256) void cvt_src_kernel(const float4* __restrict__ in,
                                                      bf16* __restrict__ out, int n4) {
  int i = blockIdx.x * 256 + threadIdx.x;
  if (i >= n4) return;
  float4 v = in[i];
  union { bf16 h[4]; uint2 u; } pk;
  pk.h[0] = __float2bfloat16(v.x);
  pk.h[1] = __float2bfloat16(v.y);
  pk.h[2] = __float2bfloat16(v.z);
  pk.h[3] = __float2bfloat16(v.w);
  *(uint2*)(out + (size_t)i * 4) = pk.u;
}

// ------------------------------------------------- transpose w -> bf16 B^T
__global__ __launch_bounds__(256) void transpose_w_kernel(const float* __restrict__ w,
                                                          bf16* __restrict__ wt) {
  __shared__ float tile[32][33];
  int x0 = blockIdx.x * 32;
  int y0 = blockIdx.y * 32;
  int tx = threadIdx.x & 31, ty = threadIdx.x >> 5;
#pragma unroll
  for (int i = 0; i < 4; i++) {
    int y = ty + i * 8;
    tile[y][tx] = w[(size_t)(y0 + y) * 3072 + x0 + tx];
  }
  __syncthreads();
#pragma unroll
  for (int i = 0; i < 4; i++) {
    int y = ty + i * 8;
    wt[(size_t)(x0 + y) * 1024 + y0 + tx] = __float2bfloat16(tile[tx][y]);
  }
}

// ------------------------------------------------------------ QKV GEMM (unchanged)
__global__ __launch_bounds__(256) void qkv_gemm_kernel(
    const bf16* __restrict__ A, const bf16* __restrict__ Bt,
    const float* __restrict__ bias,
    bf16* __restrict__ q_ws, bf16* __restrict__ k_ws, bf16* __restrict__ vt_ws) {
  __shared__ alignas(16) bf16 As[128 * 72];
  __shared__ alignas(16) bf16 Bs[128 * 72];
  const int tid = threadIdx.x;
  const int lane = tid & 63, wid = tid >> 6;
  const int lr = lane & 15, lg = lane >> 4;
  const int wm = wid >> 1, wn = wid & 1;
  const int m0 = blockIdx.x * 128, n0 = blockIdx.y * 128;

  const f32x4 z4 = {0.f, 0.f, 0.f, 0.f};
  f32x4 acc[4][4];
#pragma unroll
  for (int m = 0; m < 4; m++)
#pragma unroll
    for (int n = 0; n < 4; n++) acc[m][n] = z4;

  const int srow = tid >> 3;
  const int sseg = tid & 7;

  for (int kt = 0; kt < 16; kt++) {
    const int k0 = kt * 64;
    __syncthreads();
#pragma unroll
    for (int i = 0; i < 4; i++) {
      int row = i * 32 + srow;
      *(short8*)&As[row * 72 + sseg * 8] =
          *(const short8*)&A[(size_t)(m0 + row) * 1024 + k0 + sseg * 8];
      *(short8*)&Bs[row * 72 + sseg * 8] =
          *(const short8*)&Bt[(size_t)(n0 + row) * 1024 + k0 + sseg * 8];
    }
    __syncthreads();
#pragma unroll
    for (int g = 0; g < 2; g++) {
      short8 af[4], bfr[4];
#pragma unroll
      for (int m = 0; m < 4; m++)
        af[m] = *(const short8*)&As[(wm * 64 + m * 16 + lr) * 72 + g * 32 + lg * 8];
#pragma unroll
      for (int n = 0; n < 4; n++)
        bfr[n] = *(const short8*)&Bs[(wn * 64 + n * 16 + lr) * 72 + g * 32 + lg * 8];
#pragma unroll
      for (int m = 0; m < 4; m++)
#pragma unroll
        for (int n = 0; n < 4; n++)
          acc[m][n] = __builtin_amdgcn_mfma_f32_16x16x32_bf16(af[m], bfr[n], acc[m][n], 0, 0, 0);
    }
  }

  const int which = n0 >> 10;
#pragma unroll
  for (int m = 0; m < 4; m++) {
    int row = m0 + wm * 64 + m * 16 + lg * 4;
    int b = row >> 11;
    int ss0 = row & 2047;
#pragma unroll
    for (int n = 0; n < 4; n++) {
      int col = n0 + wn * 64 + n * 16 + lr;
      int d = col & 1023;
      int h = d >> 6, hd = d & 63;
      size_t bh = (size_t)(b * 16 + h);
      float bv = bias[col];
      if (which == 2) {
        union { bf16 h4[4]; uint2 u; } pk;
#pragma unroll
        for (int r = 0; r < 4; r++) pk.h4[r] = __float2bfloat16(acc[m][n][r] + bv);
        *(uint2*)&vt_ws[(bh * 64 + hd) * 2048 + ss0] = pk.u;
      } else {
        bf16* dst = (which == 0) ? q_ws : k_ws;
#pragma unroll
        for (int r = 0; r < 4; r++)
          dst[(bh * 2048 + (ss0 + r)) * 64 + hd] = __float2bfloat16(acc[m][n][r] + bv);
      }
    }
  }
}

// ------------------------------------------------------------ attention v3
// 8 warps x 32 q-rows = 256 q/block; grid 256 blocks (8 qb x 32 bh, XCD-grouped).
// Swapped QK^T (S^T = K*Q^T) and O^T = V^T * P^T so softmax state is lane-local.
// v3: all cross-half exchanges via __shfl_xor(.,32) (known semantics), no permlane asm.
__global__ __launch_bounds__(512) void attn2_kernel(
    const bf16* __restrict__ q_ws, const bf16* __restrict__ k_ws,
    const bf16* __restrict__ vt_ws, float* __restrict__ out) {
  // [0,16K): K tiles [2][64][64] bf16 (xor-swizzled); [16K,32K): V^T tiles
  __shared__ alignas(16) char smem[32768];
  const int tid = threadIdx.x;
  const int lane = tid & 63, wid = tid >> 6;
  const int lq = lane & 31, hi = lane >> 5;
  const int hi16 = hi * 16;
  const int xorv = (lq & 7) << 4;
  const float scale_l2e = 0.125f * 1.44269504088896f;

  // XCD-grouped decode: XCD (id%8) sees bh in a 4-head group -> 2MB K/V fits L2
  const int f = blockIdx.x;
  const int bh = (f & 7) * 4 + ((f >> 3) & 3);
  const int qb = f >> 5;
  const int b = bh >> 4, h = bh & 15;
  const int q0 = qb * 256 + wid * 32;

  // Q fragments (B operand): col=q=lane&31, k=d = s*16 + hi*8 + j
  short8 qf[4];
  {
    const bf16* qrow = q_ws + ((size_t)bh * 2048 + q0 + lq) * 64;
#pragma unroll
    for (int s = 0; s < 4; s++) qf[s] = *(const short8*)(qrow + s * 16 + hi * 8);
  }

  // staging: wave w stages rows w*8..w*8+7 of each tile; source pre-swizzled
  const int seg = (lane & 7) ^ (lane >> 3);  // involution with row&7 = lane>>3
  const char* kgl = (const char*)k_ws + (size_t)bh * 2048 * 128 +
                    (size_t)(wid * 8 + (lane >> 3)) * 128 + seg * 16;
  const char* vgl = (const char*)vt_ws + (size_t)bh * 64 * 4096 +
                    (size_t)(wid * 8 + (lane >> 3)) * 4096 + seg * 16;
  char* klds = smem + wid * 1024;
  char* vlds = smem + 16384 + wid * 1024;

  f32x16 o0, o1;
#pragma unroll
  for (int r = 0; r < 16; r++) { o0[r] = 0.f; o1[r] = 0.f; }
  float m = -1e30f, l = 0.f;

  // prologue: stage tile 0 into buf0
  glds16(kgl, klds);
  glds16(vgl, vlds);
  asm volatile("s_waitcnt vmcnt(0)" ::: "memory");
  __syncthreads();

  for (int kt = 0; kt < 32; ++kt) {
    const int cur = kt & 1;
    if (kt + 1 < 32) {  // issue next-tile loads; they fly under this tile's compute
      glds16(kgl + (size_t)(kt + 1) * 8192, klds + (cur ^ 1) * 8192);
      glds16(vgl + (size_t)(kt + 1) * 128, vlds + (cur ^ 1) * 8192);
    }
    const int curK = cur * 8192;
    const int curV = 16384 + cur * 8192;

    // ---- S^T = K * Q^T  (A=K rows from LDS, B=Q regs) ----
    f32x16 s0, s1;
#pragma unroll
    for (int r = 0; r < 16; r++) { s0[r] = 0.f; s1[r] = 0.f; }
#pragma unroll
    for (int s = 0; s < 4; s++) {
      const int doff = (s * 32 + hi16) ^ xorv;
      short8 k0 = *(const short8*)(smem + curK + lq * 128 + doff);
      short8 k1 = *(const short8*)(smem + curK + 4096 + lq * 128 + doff);
      s0 = __builtin_amdgcn_mfma_f32_32x32x16_bf16(k0, qf[s], s0, 0, 0, 0);
      s1 = __builtin_amdgcn_mfma_f32_32x32x16_bf16(k1, qf[s], s1, 0, 0, 0);
    }

    // ---- softmax, lane-local (lane pair (lq,hi) shares row q=lq) ----
    float mx[8];
#pragma unroll
    for (int r = 0; r < 16; r++) { s0[r] *= scale_l2e; s1[r] *= scale_l2e; }
#pragma unroll
    for (int i = 0; i < 8; i++) mx[i] = fmaxf(fmaxf(s0[i], s0[i + 8]), fmaxf(s1[i], s1[i + 8]));
#pragma unroll
    for (int i = 0; i < 4; i++) mx[i] = fmaxf(mx[i], mx[i + 4]);
    float pm = fmaxf(fmaxf(mx[0], mx[1]), fmaxf(mx[2], mx[3]));
    pm = fmaxf(pm, __shfl_xor(pm, 32));  // cross-half
    if (pm > m + 8.f) {  // defer-max (T13): rescale only on real max growth
      float rs = __builtin_amdgcn_exp2f(m - pm);
      m = pm; l *= rs;
#pragma unroll
      for (int r = 0; r < 16; r++) { o0[r] *= rs; o1[r] *= rs; }
    }
    float sum[8];
#pragma unroll
    for (int r = 0; r < 16; r++) {
      s0[r] = __builtin_amdgcn_exp2f(s0[r] - m);
      s1[r] = __builtin_amdgcn_exp2f(s1[r] - m);
    }
#pragma unroll
    for (int i = 0; i < 8; i++) sum[i] = (s0[i] + s0[i + 8]) + (s1[i] + s1[i + 8]);
#pragma unroll
    for (int i = 0; i < 4; i++) sum[i] += sum[i + 4];
    float ps = (sum[0] + sum[1]) + (sum[2] + sum[3]);
    ps += __shfl_xor(ps, 32);  // cross-half
    l += ps;

    // ---- O^T += V^T * P^T ;  P^T B-frags via shfl_xor(32) + select ----
    // lane (lq,hi) holds P[q=lq][key = (r&3)+8*(r>>2)+4*hi (+32 for s1)]
    // B-frag chunk c needs keys c*16 + 8*hi + j  ->
    //   hi=0: [w0,w1,t0,t1] / [w4,w5,t4,t5] ; hi=1: [t2,t3,w2,w3] / [t6,t7,w6,w7]
#pragma unroll
    for (int kb = 0; kb < 2; kb++) {
      uint w[8], t[8];
#pragma unroll
      for (int i = 0; i < 8; i++) {
        union { bf16 h2[2]; uint u; } pk;
        float plo = kb ? s1[2 * i] : s0[2 * i];
        float phi = kb ? s1[2 * i + 1] : s0[2 * i + 1];
        pk.h2[0] = __float2bfloat16(plo);
        pk.h2[1] = __float2bfloat16(phi);
        w[i] = pk.u;
      }
#pragma unroll
      for (int i = 0; i < 8; i++) t[i] = (uint)__shfl_xor((int)w[i], 32);
      union { uint u[4]; short8 s; } ua, ub;
      ua.u[0] = hi ? t[2] : w[0];
      ua.u[1] = hi ? t[3] : w[1];
      ua.u[2] = hi ? w[2] : t[0];
      ua.u[3] = hi ? w[3] : t[1];
      ub.u[0] = hi ? t[6] : w[4];
      ub.u[1] = hi ? t[7] : w[5];
      ub.u[2] = hi ? w[6] : t[4];
      ub.u[3] = hi ? w[7] : t[5];
#pragma unroll
      for (int s = 0; s < 2; s++) {
        short8 pa = s ? ub.s : ua.s;
        const int koff = (kb * 64 + s * 32 + hi16) ^ xorv;
        short8 v0 = *(const short8*)(smem + curV + lq * 128 + koff);
        short8 v1 = *(const short8*)(smem + curV + 4096 + lq * 128 + koff);
        o0 = __builtin_amdgcn_mfma_f32_32x32x16_bf16(v0, pa, o0, 0, 0, 0);
        o1 = __builtin_amdgcn_mfma_f32_32x32x16_bf16(v1, pa, o1, 0, 0, 0);
      }
    }

    asm volatile("s_waitcnt vmcnt(0)" ::: "memory");
    __syncthreads();
  }

  // ---- epilogue: 1/l (lane-local), transpose O^T->O via rotated LDS ----
  __syncthreads();  // all warps done with tiles; reuse smem as 8 x 4KB scratch
  float* ep = (float*)(smem) + wid * 1024;
  const float invl = 1.f / l;
  const int eq = lane >> 1, eds = lane & 1;
  float* obase = out + ((size_t)b * 2048 + qb * 256 + wid * 32 + eq) * 1024 +
                 h * 64 + eds * 16;
#pragma unroll
  for (int db = 0; db < 2; db++) {
#pragma unroll
    for (int r = 0; r < 16; r++) {
      int d = (r & 3) + 8 * (r >> 2) + 4 * hi;  // C row = d_local
      float v = (db ? o1[r] : o0[r]) * invl;
      ep[lq * 32 + ((d + lq) & 31)] = v;  // rotation swizzle: conflict-free both ways
    }
#pragma unroll
    for (int c = 0; c < 4; c++) {
      float4 t;
      t.x = ep[eq * 32 + ((eds * 16 + 4 * c + 0 + eq) & 31)];
      t.y = ep[eq * 32 + ((eds * 16 + 4 * c + 1 + eq) & 31)];
      t.z = ep[eq * 32 + ((eds * 16 + 4 * c + 2 + eq) & 31)];
      t.w = ep[eq * 32 + ((eds * 16 + 4 * c + 3 + eq) & 31)];
      *(float4*)(obase + db * 32 + 4 * c) = t;
    }
  }
}

// ---------------------------------------------------------------- launch
extern "C" void kernel_launch(void* const* d_in, const int* in_sizes, int n_in,
                              void* d_out, int out_size, void* d_ws, size_t ws_size,
                              hipStream_t stream) {
  (void)in_sizes; (void)n_in; (void)out_size; (void)ws_size;
  const float* src  = (const float*)d_in[0];
  const float* w    = (const float*)d_in[1];
  const float* bias = (const float*)d_in[2];
  float* out = (float*)d_out;

  char* ws = (char*)d_ws;
  bf16* src_bf = (bf16*)ws;
  bf16* wt_bf  = (bf16*)(ws + 8388608);
  bf16* q_ws   = (bf16*)(ws + 8388608 + 6291456);
  bf16* k_ws   = q_ws + 4194304;
  bf16* vt_ws  = k_ws + 4194304;

  cvt_src_kernel<<<4096, 256, 0, stream>>>((const float4*)src, src_bf, 1048576);
  transpose_w_kernel<<<dim3(96, 32), 256, 0, stream>>>(w, wt_bf);
  qkv_gemm_kernel<<<dim3(32, 24), 256, 0, stream>>>(src_bf, wt_bf, bias, q_ws, k_ws, vt_ws);
  attn2_kernel<<<256, 512, 0, stream>>>(q_ws, k_ws, vt_ws, out);
}

// Round 4
// 107.692 us; speedup vs baseline: 1.6781x; 1.0912x over previous
//
#include <hip/hip_runtime.h>
#include <hip/hip_bf16.h>

typedef short short8 __attribute__((ext_vector_type(8)));
typedef float f32x4 __attribute__((ext_vector_type(4)));
typedef float f32x16 __attribute__((ext_vector_type(16)));
typedef __hip_bfloat16 bf16;

// Problem constants: B=2, S=2048, D=1024, H=16, HD=64, SCALE=1/8

__device__ __forceinline__ void glds16(const void* g, void* l) {
  __builtin_amdgcn_global_load_lds((const __attribute__((address_space(1))) unsigned int*)g,
                                   (__attribute__((address_space(3))) unsigned int*)l, 16, 0, 0);
}

// ---------------------------------------------------------------- cvt src
__global__ __launch_bounds__(256) void cvt_src_kernel(const float4* __restrict__ in,
                                                      bf16* __restrict__ out, int n4) {
  int i = blockIdx.x * 256 + threadIdx.x;
  if (i >= n4) return;
  float4 v = in[i];
  union { bf16 h[4]; uint2 u; } pk;
  pk.h[0] = __float2bfloat16(v.x);
  pk.h[1] = __float2bfloat16(v.y);
  pk.h[2] = __float2bfloat16(v.z);
  pk.h[3] = __float2bfloat16(v.w);
  *(uint2*)(out + (size_t)i * 4) = pk.u;
}

// ------------------------------------------------- transpose w -> bf16 B^T
__global__ __launch_bounds__(256) void transpose_w_kernel(const float* __restrict__ w,
                                                          bf16* __restrict__ wt) {
  __shared__ float tile[32][33];
  int x0 = blockIdx.x * 32;
  int y0 = blockIdx.y * 32;
  int tx = threadIdx.x & 31, ty = threadIdx.x >> 5;
#pragma unroll
  for (int i = 0; i < 4; i++) {
    int y = ty + i * 8;
    tile[y][tx] = w[(size_t)(y0 + y) * 3072 + x0 + tx];
  }
  __syncthreads();
#pragma unroll
  for (int i = 0; i < 4; i++) {
    int y = ty + i * 8;
    wt[(size_t)(x0 + y) * 1024 + y0 + tx] = __float2bfloat16(tile[tx][y]);
  }
}

// ------------------------------------------------------------ QKV GEMM v2
// glds16 staging, linear LDS [row][64] (128B rows) with XOR-swizzle (rule 21):
// LDS(row, seg16) holds global(row, seg16 ^ (row&7)); reads XOR the same.
__global__ __launch_bounds__(256) void qkv_gemm_kernel(
    const bf16* __restrict__ A, const bf16* __restrict__ Bt,
    const float* __restrict__ bias,
    bf16* __restrict__ q_ws, bf16* __restrict__ k_ws, bf16* __restrict__ vt_ws) {
  __shared__ alignas(16) char AB[32768];  // As [0,16K), Bs [16K,32K)
  const int tid = threadIdx.x;
  const int lane = tid & 63, wid = tid >> 6;
  const int lr = lane & 15, lg = lane >> 4;
  const int wm = wid >> 1, wn = wid & 1;
  const int m0 = blockIdx.x * 128, n0 = blockIdx.y * 128;

  const f32x4 z4 = {0.f, 0.f, 0.f, 0.f};
  f32x4 acc[4][4];
#pragma unroll
  for (int m = 0; m < 4; m++)
#pragma unroll
    for (int n = 0; n < 4; n++) acc[m][n] = z4;

  // staging: wave w stages rows w*32 + c*8 + (lane>>3), seg (lane&7)^(lane>>3)
  const int srow = lane >> 3;
  const int sseg = (lane & 7) ^ srow;
  const char* Ag = (const char*)A + (size_t)(m0 + wid * 32 + srow) * 2048 + sseg * 16;
  const char* Bg = (const char*)Bt + (size_t)(n0 + wid * 32 + srow) * 2048 + sseg * 16;
  char* Al = AB + wid * 4096;
  char* Bl = AB + 16384 + wid * 4096;
  const int xora = (lr & 7) << 4;

  for (int kt = 0; kt < 16; kt++) {
    __syncthreads();  // previous compute done before overwrite
#pragma unroll
    for (int c = 0; c < 4; c++) {
      glds16(Ag + (size_t)kt * 128 + c * 16384, Al + c * 1024);
      glds16(Bg + (size_t)kt * 128 + c * 16384, Bl + c * 1024);
    }
    asm volatile("s_waitcnt vmcnt(0)" ::: "memory");
    __syncthreads();
#pragma unroll
    for (int g = 0; g < 2; g++) {
      short8 af[4], bfr[4];
#pragma unroll
      for (int m = 0; m < 4; m++)
        af[m] = *(const short8*)(AB + (wm * 64 + m * 16 + lr) * 128 +
                                 ((g * 64 + lg * 16) ^ xora));
#pragma unroll
      for (int n = 0; n < 4; n++)
        bfr[n] = *(const short8*)(AB + 16384 + (wn * 64 + n * 16 + lr) * 128 +
                                  ((g * 64 + lg * 16) ^ xora));
#pragma unroll
      for (int m = 0; m < 4; m++)
#pragma unroll
        for (int n = 0; n < 4; n++)
          acc[m][n] = __builtin_amdgcn_mfma_f32_16x16x32_bf16(af[m], bfr[n], acc[m][n], 0, 0, 0);
    }
  }

  const int which = n0 >> 10;
#pragma unroll
  for (int m = 0; m < 4; m++) {
    int row = m0 + wm * 64 + m * 16 + lg * 4;
    int b = row >> 11;
    int ss0 = row & 2047;
#pragma unroll
    for (int n = 0; n < 4; n++) {
      int col = n0 + wn * 64 + n * 16 + lr;
      int d = col & 1023;
      int h = d >> 6, hd = d & 63;
      size_t bh = (size_t)(b * 16 + h);
      float bv = bias[col];
      if (which == 2) {
        union { bf16 h4[4]; uint2 u; } pk;
#pragma unroll
        for (int r = 0; r < 4; r++) pk.h4[r] = __float2bfloat16(acc[m][n][r] + bv);
        *(uint2*)&vt_ws[(bh * 64 + hd) * 2048 + ss0] = pk.u;
      } else {
        bf16* dst = (which == 0) ? q_ws : k_ws;
#pragma unroll
        for (int r = 0; r < 4; r++)
          dst[(bh * 2048 + (ss0 + r)) * 64 + hd] = __float2bfloat16(acc[m][n][r] + bv);
      }
    }
  }
}

// ------------------------------------------------------------ attention v4
// v3 compute body (verified) + depth-3 prefetch, 4 LDS buffers, counted vmcnt,
// raw s_barrier (no implicit drain), setprio around MFMA clusters.
__global__ __launch_bounds__(512) void attn2_kernel(
    const bf16* __restrict__ q_ws, const bf16* __restrict__ k_ws,
    const bf16* __restrict__ vt_ws, float* __restrict__ out) {
  // [0,32K): K bufs [4][64][64] bf16 (xor-swizzled); [32K,64K): V^T bufs
  __shared__ alignas(16) char smem[65536];
  const int tid = threadIdx.x;
  const int lane = tid & 63, wid = tid >> 6;
  const int lq = lane & 31, hi = lane >> 5;
  const int hi16 = hi * 16;
  const int xorv = (lq & 7) << 4;
  const float scale_l2e = 0.125f * 1.44269504088896f;

  // XCD-grouped decode: XCD (id%8) sees bh in a 4-head group -> 2MB K/V fits L2
  const int f = blockIdx.x;
  const int bh = (f & 7) * 4 + ((f >> 3) & 3);
  const int qb = f >> 5;
  const int b = bh >> 4, h = bh & 15;
  const int q0 = qb * 256 + wid * 32;

  // Q fragments (B operand): col=q=lane&31, k=d = s*16 + hi*8 + j
  short8 qf[4];
  {
    const bf16* qrow = q_ws + ((size_t)bh * 2048 + q0 + lq) * 64;
#pragma unroll
    for (int s = 0; s < 4; s++) qf[s] = *(const short8*)(qrow + s * 16 + hi * 8);
  }

  // staging: wave w stages rows w*8..w*8+7 of each tile; source pre-swizzled
  const int seg = (lane & 7) ^ (lane >> 3);
  const char* kgl = (const char*)k_ws + (size_t)bh * 2048 * 128 +
                    (size_t)(wid * 8 + (lane >> 3)) * 128 + seg * 16;
  const char* vgl = (const char*)vt_ws + (size_t)bh * 64 * 4096 +
                    (size_t)(wid * 8 + (lane >> 3)) * 4096 + seg * 16;

  f32x16 o0, o1;
#pragma unroll
  for (int r = 0; r < 16; r++) { o0[r] = 0.f; o1[r] = 0.f; }
  float m = -1e30f, l = 0.f;

  // prologue: stage tiles 0,1,2 into bufs 0,1,2 (6 glds outstanding)
#pragma unroll
  for (int p = 0; p < 3; p++) {
    glds16(kgl + (size_t)p * 8192, smem + p * 8192 + wid * 1024);
    glds16(vgl + (size_t)p * 128, smem + 32768 + p * 8192 + wid * 1024);
  }
  asm volatile("s_waitcnt vmcnt(4)" ::: "memory");  // tile 0 landed
  __builtin_amdgcn_s_barrier();

  for (int kt = 0; kt < 32; ++kt) {
    const int buf = kt & 3;
    if (kt + 3 < 32) {  // stage tile kt+3 into buf (kt+3)&3 == (kt-1)&3 (free now)
      glds16(kgl + (size_t)(kt + 3) * 8192, smem + ((kt + 3) & 3) * 8192 + wid * 1024);
      glds16(vgl + (size_t)(kt + 3) * 128, smem + 32768 + ((kt + 3) & 3) * 8192 + wid * 1024);
    }
    const int curK = buf * 8192;
    const int curV = 32768 + buf * 8192;

    // ---- S^T = K * Q^T  (A=K rows from LDS, B=Q regs) ----
    f32x16 s0, s1;
#pragma unroll
    for (int r = 0; r < 16; r++) { s0[r] = 0.f; s1[r] = 0.f; }
#pragma unroll
    for (int s = 0; s < 4; s++) {
      const int doff = (s * 32 + hi16) ^ xorv;
      short8 k0 = *(const short8*)(smem + curK + lq * 128 + doff);
      short8 k1 = *(const short8*)(smem + curK + 4096 + lq * 128 + doff);
      __builtin_amdgcn_s_setprio(1);
      s0 = __builtin_amdgcn_mfma_f32_32x32x16_bf16(k0, qf[s], s0, 0, 0, 0);
      s1 = __builtin_amdgcn_mfma_f32_32x32x16_bf16(k1, qf[s], s1, 0, 0, 0);
      __builtin_amdgcn_s_setprio(0);
    }

    // ---- softmax, lane-local (lane pair (lq,hi) shares row q=lq) ----
    float mx[8];
#pragma unroll
    for (int r = 0; r < 16; r++) { s0[r] *= scale_l2e; s1[r] *= scale_l2e; }
#pragma unroll
    for (int i = 0; i < 8; i++) mx[i] = fmaxf(fmaxf(s0[i], s0[i + 8]), fmaxf(s1[i], s1[i + 8]));
#pragma unroll
    for (int i = 0; i < 4; i++) mx[i] = fmaxf(mx[i], mx[i + 4]);
    float pm = fmaxf(fmaxf(mx[0], mx[1]), fmaxf(mx[2], mx[3]));
    pm = fmaxf(pm, __shfl_xor(pm, 32));  // cross-half
    if (pm > m + 8.f) {  // defer-max (T13)
      float rs = __builtin_amdgcn_exp2f(m - pm);
      m = pm; l *= rs;
#pragma unroll
      for (int r = 0; r < 16; r++) { o0[r] *= rs; o1[r] *= rs; }
    }
    float sum[8];
#pragma unroll
    for (int r = 0; r < 16; r++) {
      s0[r] = __builtin_amdgcn_exp2f(s0[r] - m);
      s1[r] = __builtin_amdgcn_exp2f(s1[r] - m);
    }
#pragma unroll
    for (int i = 0; i < 8; i++) sum[i] = (s0[i] + s0[i + 8]) + (s1[i] + s1[i + 8]);
#pragma unroll
    for (int i = 0; i < 4; i++) sum[i] += sum[i + 4];
    float ps = (sum[0] + sum[1]) + (sum[2] + sum[3]);
    ps += __shfl_xor(ps, 32);
    l += ps;

    // ---- O^T += V^T * P^T ;  P^T B-frags via shfl_xor(32) + select ----
#pragma unroll
    for (int kb = 0; kb < 2; kb++) {
      uint w[8], t[8];
#pragma unroll
      for (int i = 0; i < 8; i++) {
        union { bf16 h2[2]; uint u; } pk;
        float plo = kb ? s1[2 * i] : s0[2 * i];
        float phi = kb ? s1[2 * i + 1] : s0[2 * i + 1];
        pk.h2[0] = __float2bfloat16(plo);
        pk.h2[1] = __float2bfloat16(phi);
        w[i] = pk.u;
      }
#pragma unroll
      for (int i = 0; i < 8; i++) t[i] = (uint)__shfl_xor((int)w[i], 32);
      union { uint u[4]; short8 s; } ua, ub;
      ua.u[0] = hi ? t[2] : w[0];
      ua.u[1] = hi ? t[3] : w[1];
      ua.u[2] = hi ? w[2] : t[0];
      ua.u[3] = hi ? w[3] : t[1];
      ub.u[0] = hi ? t[6] : w[4];
      ub.u[1] = hi ? t[7] : w[5];
      ub.u[2] = hi ? w[6] : t[4];
      ub.u[3] = hi ? w[7] : t[5];
#pragma unroll
      for (int s = 0; s < 2; s++) {
        short8 pa = s ? ub.s : ua.s;
        const int koff = (kb * 64 + s * 32 + hi16) ^ xorv;
        short8 v0 = *(const short8*)(smem + curV + lq * 128 + koff);
        short8 v1 = *(const short8*)(smem + curV + 4096 + lq * 128 + koff);
        __builtin_amdgcn_s_setprio(1);
        o0 = __builtin_amdgcn_mfma_f32_32x32x16_bf16(v0, pa, o0, 0, 0, 0);
        o1 = __builtin_amdgcn_mfma_f32_32x32x16_bf16(v1, pa, o1, 0, 0, 0);
        __builtin_amdgcn_s_setprio(0);
      }
    }

    // counted wait: ensure tile kt+1's loads (the oldest outstanding) landed
    if (kt < 29)       asm volatile("s_waitcnt vmcnt(4)" ::: "memory");
    else if (kt == 29) asm volatile("s_waitcnt vmcnt(2)" ::: "memory");
    else if (kt == 30) asm volatile("s_waitcnt vmcnt(0)" ::: "memory");
    if (kt < 31) __builtin_amdgcn_s_barrier();
  }
  __syncthreads();  // full drain before epilogue smem reuse

  // ---- epilogue: 1/l (lane-local), transpose O^T->O via rotated LDS ----
  float* ep = (float*)(smem) + wid * 1024;
  const float invl = 1.f / l;
  const int eq = lane >> 1, eds = lane & 1;
  float* obase = out + ((size_t)b * 2048 + qb * 256 + wid * 32 + eq) * 1024 +
                 h * 64 + eds * 16;
#pragma unroll
  for (int db = 0; db < 2; db++) {
#pragma unroll
    for (int r = 0; r < 16; r++) {
      int d = (r & 3) + 8 * (r >> 2) + 4 * hi;  // C row = d_local
      float v = (db ? o1[r] : o0[r]) * invl;
      ep[lq * 32 + ((d + lq) & 31)] = v;  // rotation swizzle
    }
#pragma unroll
    for (int c = 0; c < 4; c++) {
      float4 t;
      t.x = ep[eq * 32 + ((eds * 16 + 4 * c + 0 + eq) & 31)];
      t.y = ep[eq * 32 + ((eds * 16 + 4 * c + 1 + eq) & 31)];
      t.z = ep[eq * 32 + ((eds * 16 + 4 * c + 2 + eq) & 31)];
      t.w = ep[eq * 32 + ((eds * 16 + 4 * c + 3 + eq) & 31)];
      *(float4*)(obase + db * 32 + 4 * c) = t;
    }
  }
}

// ---------------------------------------------------------------- launch
extern "C" void kernel_launch(void* const* d_in, const int* in_sizes, int n_in,
                              void* d_out, int out_size, void* d_ws, size_t ws_size,
                              hipStream_t stream) {
  (void)in_sizes; (void)n_in; (void)out_size; (void)ws_size;
  const float* src  = (const float*)d_in[0];
  const float* w    = (const float*)d_in[1];
  const float* bias = (const float*)d_in[2];
  float* out = (float*)d_out;

  char* ws = (char*)d_ws;
  bf16* src_bf = (bf16*)ws;
  bf16* wt_bf  = (bf16*)(ws + 8388608);
  bf16* q_ws   = (bf16*)(ws + 8388608 + 6291456);
  bf16* k_ws   = q_ws + 4194304;
  bf16* vt_ws  = k_ws + 4194304;

  cvt_src_kernel<<<4096, 256, 0, stream>>>((const float4*)src, src_bf, 1048576);
  transpose_w_kernel<<<dim3(96, 32), 256, 0, stream>>>(w, wt_bf);
  qkv_gemm_kernel<<<dim3(32, 24), 256, 0, stream>>>(src_bf, wt_bf, bias, q_ws, k_ws, vt_ws);
  attn2_kernel<<<256, 512, 0, stream>>>(q_ws, k_ws, vt_ws, out);
}